// Round 2
// baseline (271.838 us; speedup 1.0000x reference)
//
#include <hip/hip_runtime.h>

static constexpr int OHW = 12, NSP = 144;

// ---------------------------------------------------------------------------
// build_T: gather x (4,256,14,14) -> T[n][k][i], n = b*144+oh*12+ow,
// k = (kh*3+kw)*32 + ic, i in [0,8). One float4 (4 consecutive i) per thread.
// (~4 us; fusing it into caps_main was tried and regressed phase 1 by 11 us.)
// ---------------------------------------------------------------------------
__global__ void build_T(const float* __restrict__ x, float4* __restrict__ T4) {
    const int g = blockIdx.x * 256 + threadIdx.x;   // [0, 576*576)
    const int n = g / 576;                          // 576 float4 per n
    const int q = g - n * 576;
    const int r = q << 2;                           // float offset in row
    const int k = r >> 3;
    const int i0 = r & 7;                           // 0 or 4
    const int ic = k & 31;
    const int kk = k >> 5;
    const int kh = kk / 3, kw = kk - kh * 3;
    const int b = n / NSP;
    const int rm = n - b * NSP;
    const int oh = rm / OHW, ow = rm - oh * OHW;
    const float* xp = x + (size_t)(b * 256 + ic * 8 + i0) * 196
                        + (oh + kh) * 14 + (ow + kw);
    float4 v;
    v.x = xp[0];
    v.y = xp[196];
    v.z = xp[392];
    v.w = xp[588];
    T4[g] = v;
}

__device__ __forceinline__ void fma4(float4& a, float s, const float4& w) {
    a.x = fmaf(s, w.x, a.x);
    a.y = fmaf(s, w.y, a.y);
    a.z = fmaf(s, w.z, a.z);
    a.w = fmaf(s, w.w, a.w);
}

__device__ __forceinline__ float4 shfl_xor4(const float4& v, int m) {
    float4 r;
    r.x = __shfl_xor(v.x, m);
    r.y = __shfl_xor(v.y, m);
    r.z = __shfl_xor(v.z, m);
    r.w = __shfl_xor(v.w, m);
    return r;
}

// Compute one (j) group: load w[8] once, produce 4 n's prior quads, write LDS.
// LDS write address = const + lane  (lane-consecutive, conflict-free b128).
// Slab stride is 6 groups now (3-chunk handoff).
__device__ __forceinline__ void do_j(const float4* __restrict__ T4,
                                     const float4* __restrict__ W4,
                                     float4* __restrict__ Pl,
                                     int o, int nbase, int k, int cg,
                                     int g_local, int lane) {
    float4 w[8];
    const float4* wp = W4 + (size_t)(o * 288 + k) * 32 + cg;
    #pragma unroll
    for (int i = 0; i < 8; ++i) w[i] = wp[i * 4];
    #pragma unroll
    for (int nn = 0; nn < 4; ++nn) {
        const float4* tp = T4 + (size_t)(nbase + nn) * 576 + k * 2;
        const float4 t0 = tp[0];
        const float4 t1 = tp[1];
        float4 a = make_float4(0.f, 0.f, 0.f, 0.f);
        fma4(a, t0.x, w[0]); fma4(a, t0.y, w[1]);
        fma4(a, t0.z, w[2]); fma4(a, t0.w, w[3]);
        fma4(a, t1.x, w[4]); fma4(a, t1.y, w[5]);
        fma4(a, t1.z, w[6]); fma4(a, t1.w, w[7]);
        Pl[nn * 384 + g_local * 64 + lane] = a;
    }
}

// ---------------------------------------------------------------------------
// caps_main: block = (o, 4 n's). Phase 1: priors GEMM, thread = (cg, kg),
// 4-n weight amortization in registers. Handoff: THREE 6-slab LDS chunks
// (24,576 B -> 6 blocks/CU = 24 waves/CU, was 4 blocks/36,864 B), layout
// [nn][g][kgp][cg]. Critical path unchanged: max 2 do_j per wave per chunk
// (was 3 per chunk x 2 chunks). Phase 2: wave = one n, lane = (cg, kgp),
// k = kgp + 16*jj; routing fully intra-wave: k-reduce = shfl_xor {4,8,16,32},
// c-reduce = shfl_xor {1,2}.
// ---------------------------------------------------------------------------
__global__ __launch_bounds__(256, 6)
void caps_main(const float4* __restrict__ T4, const float4* __restrict__ W4,
               float* __restrict__ out) {
    __shared__ float4 Pl[4 * 6 * 64];   // 24,576 B -> 6 blocks/CU
    const int tid = threadIdx.x;
    const int o = blockIdx.y;
    const int nbase = blockIdx.x * 4;
    const int cg = tid & 3;
    const int kg = tid >> 2;     // [0,64)
    const int wv = tid >> 6;
    const int lane = tid & 63;

    float4 P[18];

    // ---- phase 1, chunk 0: g = wv + 4j in [0,6) ----
    #pragma unroll
    for (int j = 0; j < 5; ++j) {
        const int k = kg + 64 * j;
        const int g = wv + 4 * j;
        if (k < 288 && g < 6)
            do_j(T4, W4, Pl, o, nbase, k, cg, g, lane);
    }
    __syncthreads();
    #pragma unroll
    for (int jj = 0; jj < 6; ++jj)
        P[jj] = Pl[wv * 384 + jj * 64 + lane];
    __syncthreads();

    // ---- phase 1, chunk 1: g in [6,12) ----
    #pragma unroll
    for (int j = 0; j < 5; ++j) {
        const int k = kg + 64 * j;
        const int g = wv + 4 * j;
        if (k < 288 && g >= 6 && g < 12)
            do_j(T4, W4, Pl, o, nbase, k, cg, g - 6, lane);
    }
    __syncthreads();
    #pragma unroll
    for (int jj = 6; jj < 12; ++jj)
        P[jj] = Pl[wv * 384 + (jj - 6) * 64 + lane];
    __syncthreads();

    // ---- phase 1, chunk 2: g in [12,18) ----
    #pragma unroll
    for (int j = 0; j < 5; ++j) {
        const int k = kg + 64 * j;
        const int g = wv + 4 * j;
        if (k < 288 && g >= 12)
            do_j(T4, W4, Pl, o, nbase, k, cg, g - 12, lane);
    }
    __syncthreads();
    #pragma unroll
    for (int jj = 12; jj < 18; ++jj)
        P[jj] = Pl[wv * 384 + (jj - 12) * 64 + lane];

    // ---- phase 2: dynamic routing, wave = n (= nbase + wv) ----
    float lj[18];
    #pragma unroll
    for (int jj = 0; jj < 18; ++jj) lj[jj] = 0.f;
    float4 vq = make_float4(0.f, 0.f, 0.f, 0.f);

    #pragma unroll
    for (int it = 0; it < 3; ++it) {
        float4 svU = make_float4(0.f, 0.f, 0.f, 0.f);
        float S;
        if (it == 0) {
            #pragma unroll
            for (int jj = 0; jj < 18; ++jj) {
                svU.x += P[jj].x; svU.y += P[jj].y;
                svU.z += P[jj].z; svU.w += P[jj].w;
            }
            #pragma unroll
            for (int m = 4; m < 64; m <<= 1) {
                const float4 t = shfl_xor4(svU, m);
                svU.x += t.x; svU.y += t.y; svU.z += t.z; svU.w += t.w;
            }
            S = 288.0f;
        } else {
            S = 0.f;
            #pragma unroll
            for (int jj = 0; jj < 18; ++jj) {
                const float e = __expf(lj[jj]);   // |lj| small; no max needed
                S += e;
                fma4(svU, e, P[jj]);
            }
            #pragma unroll
            for (int m = 4; m < 64; m <<= 1) {
                const float4 t = shfl_xor4(svU, m);
                svU.x += t.x; svU.y += t.y; svU.z += t.z; svU.w += t.w;
                S += __shfl_xor(S, m);
            }
        }
        const float invS = __frcp_rn(S);
        float4 s;
        s.x = svU.x * invS; s.y = svU.y * invS;
        s.z = svU.z * invS; s.w = svU.w * invS;
        float sq = s.x * s.x + s.y * s.y + s.z * s.z + s.w * s.w;
        sq += __shfl_xor(sq, 1);
        sq += __shfl_xor(sq, 2);
        const float scale = __fsqrt_rn(sq) / (1.0f + sq);
        vq.x = s.x * scale; vq.y = s.y * scale;
        vq.z = s.z * scale; vq.w = s.w * scale;

        if (it < 2) {
            #pragma unroll
            for (int jj = 0; jj < 18; ++jj) {
                float d = P[jj].x * vq.x + P[jj].y * vq.y +
                          P[jj].z * vq.z + P[jj].w * vq.w;
                d += __shfl_xor(d, 1);
                d += __shfl_xor(d, 2);
                lj[jj] += d;
            }
        }
    }

    // ---- store: lanes kgp==0 write their c-quad ----
    if ((lane >> 2) == 0) {
        const int n = nbase + wv;
        const int b = n / NSP;
        const int rm = n - b * NSP;
        float* op = out + (size_t)(b * 512 + o * 16 + cg * 4) * NSP + rm;
        op[0 * NSP] = vq.x;
        op[1 * NSP] = vq.y;
        op[2 * NSP] = vq.z;
        op[3 * NSP] = vq.w;
    }
}

extern "C" void kernel_launch(void* const* d_in, const int* in_sizes, int n_in,
                              void* d_out, int out_size, void* d_ws, size_t ws_size,
                              hipStream_t stream) {
    const float* x  = (const float*)d_in[0];   // (4, 256, 14, 14)
    const float* wt = (const float*)d_in[1];   // (32, 288, 8, 16)
    float* out = (float*)d_out;                // (4, 512, 12, 12)
    float4* T4 = (float4*)d_ws;                // 576*2304 floats = 5.3 MB

    build_T<<<dim3(576 * 576 / 256), 256, 0, stream>>>(x, T4);
    caps_main<<<dim3(144, 32), 256, 0, stream>>>(T4, (const float4*)wt, out);
}

// Round 3
// 128.933 us; speedup vs baseline: 2.1084x; 2.1084x over previous
//
#include <hip/hip_runtime.h>

static constexpr int OHW = 12, NSP = 144;

// ---------------------------------------------------------------------------
// build_T: gather x (4,256,14,14) -> T[n][k][i], n = b*144+oh*12+ow,
// k = (kh*3+kw)*32 + ic, i in [0,8). One float4 (4 consecutive i) per thread.
// (~4 us; fusing it into caps_main was tried and regressed phase 1 by 11 us.)
// ---------------------------------------------------------------------------
__global__ void build_T(const float* __restrict__ x, float4* __restrict__ T4) {
    const int g = blockIdx.x * 256 + threadIdx.x;   // [0, 576*576)
    const int n = g / 576;                          // 576 float4 per n
    const int q = g - n * 576;
    const int r = q << 2;                           // float offset in row
    const int k = r >> 3;
    const int i0 = r & 7;                           // 0 or 4
    const int ic = k & 31;
    const int kk = k >> 5;
    const int kh = kk / 3, kw = kk - kh * 3;
    const int b = n / NSP;
    const int rm = n - b * NSP;
    const int oh = rm / OHW, ow = rm - oh * OHW;
    const float* xp = x + (size_t)(b * 256 + ic * 8 + i0) * 196
                        + (oh + kh) * 14 + (ow + kw);
    float4 v;
    v.x = xp[0];
    v.y = xp[196];
    v.z = xp[392];
    v.w = xp[588];
    T4[g] = v;
}

__device__ __forceinline__ void fma4(float4& a, float s, const float4& w) {
    a.x = fmaf(s, w.x, a.x);
    a.y = fmaf(s, w.y, a.y);
    a.z = fmaf(s, w.z, a.z);
    a.w = fmaf(s, w.w, a.w);
}

__device__ __forceinline__ float4 shfl_xor4(const float4& v, int m) {
    float4 r;
    r.x = __shfl_xor(v.x, m);
    r.y = __shfl_xor(v.y, m);
    r.z = __shfl_xor(v.z, m);
    r.w = __shfl_xor(v.w, m);
    return r;
}

// Compute one (j) group: load w[8] once, produce 4 n's prior quads, write LDS.
// LDS write address = const + lane  (lane-consecutive, conflict-free b128).
// Slab stride is 6 groups (3-chunk handoff).
__device__ __forceinline__ void do_j(const float4* __restrict__ T4,
                                     const float4* __restrict__ W4,
                                     float4* __restrict__ Pl,
                                     int o, int nbase, int k, int cg,
                                     int g_local, int lane) {
    float4 w[8];
    const float4* wp = W4 + (size_t)(o * 288 + k) * 32 + cg;
    #pragma unroll
    for (int i = 0; i < 8; ++i) w[i] = wp[i * 4];
    #pragma unroll
    for (int nn = 0; nn < 4; ++nn) {
        const float4* tp = T4 + (size_t)(nbase + nn) * 576 + k * 2;
        const float4 t0 = tp[0];
        const float4 t1 = tp[1];
        float4 a = make_float4(0.f, 0.f, 0.f, 0.f);
        fma4(a, t0.x, w[0]); fma4(a, t0.y, w[1]);
        fma4(a, t0.z, w[2]); fma4(a, t0.w, w[3]);
        fma4(a, t1.x, w[4]); fma4(a, t1.y, w[5]);
        fma4(a, t1.z, w[6]); fma4(a, t1.w, w[7]);
        Pl[nn * 384 + g_local * 64 + lane] = a;
    }
}

// ---------------------------------------------------------------------------
// caps_main: block = (o, 4 n's). Phase 1: priors GEMM, thread = (cg, kg),
// 4-n weight amortization in registers. Handoff: THREE 6-slab LDS chunks
// (24,576 B -> LDS permits 6 blocks/CU = 24 waves/CU). launch_bounds stays
// (256, 4): asking for 6 waves/EU capped VGPRs at 40 and spilled P[18] to
// scratch (850 MB of HBM spill traffic, 3x slowdown -- round 2 lesson).
// With the natural 64-VGPR allocation the register file alone allows 8
// waves/EU, so occupancy is LDS-limited at 6 blocks/CU as intended.
// Phase 2: wave = one n, lane = (cg, kgp), k = kgp + 16*jj; routing fully
// intra-wave: k-reduce = shfl_xor {4,8,16,32}, c-reduce = shfl_xor {1,2}.
// ---------------------------------------------------------------------------
__global__ __launch_bounds__(256, 4)
void caps_main(const float4* __restrict__ T4, const float4* __restrict__ W4,
               float* __restrict__ out) {
    __shared__ float4 Pl[4 * 6 * 64];   // 24,576 B -> 6 blocks/CU
    const int tid = threadIdx.x;
    const int o = blockIdx.y;
    const int nbase = blockIdx.x * 4;
    const int cg = tid & 3;
    const int kg = tid >> 2;     // [0,64)
    const int wv = tid >> 6;
    const int lane = tid & 63;

    float4 P[18];

    // ---- phase 1, chunk 0: g = wv + 4j in [0,6) ----
    #pragma unroll
    for (int j = 0; j < 5; ++j) {
        const int k = kg + 64 * j;
        const int g = wv + 4 * j;
        if (k < 288 && g < 6)
            do_j(T4, W4, Pl, o, nbase, k, cg, g, lane);
    }
    __syncthreads();
    #pragma unroll
    for (int jj = 0; jj < 6; ++jj)
        P[jj] = Pl[wv * 384 + jj * 64 + lane];
    __syncthreads();

    // ---- phase 1, chunk 1: g in [6,12) ----
    #pragma unroll
    for (int j = 0; j < 5; ++j) {
        const int k = kg + 64 * j;
        const int g = wv + 4 * j;
        if (k < 288 && g >= 6 && g < 12)
            do_j(T4, W4, Pl, o, nbase, k, cg, g - 6, lane);
    }
    __syncthreads();
    #pragma unroll
    for (int jj = 6; jj < 12; ++jj)
        P[jj] = Pl[wv * 384 + (jj - 6) * 64 + lane];
    __syncthreads();

    // ---- phase 1, chunk 2: g in [12,18) ----
    #pragma unroll
    for (int j = 0; j < 5; ++j) {
        const int k = kg + 64 * j;
        const int g = wv + 4 * j;
        if (k < 288 && g >= 12)
            do_j(T4, W4, Pl, o, nbase, k, cg, g - 12, lane);
    }
    __syncthreads();
    #pragma unroll
    for (int jj = 12; jj < 18; ++jj)
        P[jj] = Pl[wv * 384 + (jj - 12) * 64 + lane];

    // ---- phase 2: dynamic routing, wave = n (= nbase + wv) ----
    float lj[18];
    #pragma unroll
    for (int jj = 0; jj < 18; ++jj) lj[jj] = 0.f;
    float4 vq = make_float4(0.f, 0.f, 0.f, 0.f);

    #pragma unroll
    for (int it = 0; it < 3; ++it) {
        float4 svU = make_float4(0.f, 0.f, 0.f, 0.f);
        float S;
        if (it == 0) {
            #pragma unroll
            for (int jj = 0; jj < 18; ++jj) {
                svU.x += P[jj].x; svU.y += P[jj].y;
                svU.z += P[jj].z; svU.w += P[jj].w;
            }
            #pragma unroll
            for (int m = 4; m < 64; m <<= 1) {
                const float4 t = shfl_xor4(svU, m);
                svU.x += t.x; svU.y += t.y; svU.z += t.z; svU.w += t.w;
            }
            S = 288.0f;
        } else {
            S = 0.f;
            #pragma unroll
            for (int jj = 0; jj < 18; ++jj) {
                const float e = __expf(lj[jj]);   // |lj| small; no max needed
                S += e;
                fma4(svU, e, P[jj]);
            }
            #pragma unroll
            for (int m = 4; m < 64; m <<= 1) {
                const float4 t = shfl_xor4(svU, m);
                svU.x += t.x; svU.y += t.y; svU.z += t.z; svU.w += t.w;
                S += __shfl_xor(S, m);
            }
        }
        const float invS = __frcp_rn(S);
        float4 s;
        s.x = svU.x * invS; s.y = svU.y * invS;
        s.z = svU.z * invS; s.w = svU.w * invS;
        float sq = s.x * s.x + s.y * s.y + s.z * s.z + s.w * s.w;
        sq += __shfl_xor(sq, 1);
        sq += __shfl_xor(sq, 2);
        const float scale = __fsqrt_rn(sq) / (1.0f + sq);
        vq.x = s.x * scale; vq.y = s.y * scale;
        vq.z = s.z * scale; vq.w = s.w * scale;

        if (it < 2) {
            #pragma unroll
            for (int jj = 0; jj < 18; ++jj) {
                float d = P[jj].x * vq.x + P[jj].y * vq.y +
                          P[jj].z * vq.z + P[jj].w * vq.w;
                d += __shfl_xor(d, 1);
                d += __shfl_xor(d, 2);
                lj[jj] += d;
            }
        }
    }

    // ---- store: lanes kgp==0 write their c-quad ----
    if ((lane >> 2) == 0) {
        const int n = nbase + wv;
        const int b = n / NSP;
        const int rm = n - b * NSP;
        float* op = out + (size_t)(b * 512 + o * 16 + cg * 4) * NSP + rm;
        op[0 * NSP] = vq.x;
        op[1 * NSP] = vq.y;
        op[2 * NSP] = vq.z;
        op[3 * NSP] = vq.w;
    }
}

extern "C" void kernel_launch(void* const* d_in, const int* in_sizes, int n_in,
                              void* d_out, int out_size, void* d_ws, size_t ws_size,
                              hipStream_t stream) {
    const float* x  = (const float*)d_in[0];   // (4, 256, 14, 14)
    const float* wt = (const float*)d_in[1];   // (32, 288, 8, 16)
    float* out = (float*)d_out;                // (4, 512, 12, 12)
    float4* T4 = (float4*)d_ws;                // 576*2304 floats = 5.3 MB

    build_T<<<dim3(576 * 576 / 256), 256, 0, stream>>>(x, T4);
    caps_main<<<dim3(144, 32), 256, 0, stream>>>(T4, (const float4*)wt, out);
}